// Round 5
// baseline (69.739 us; speedup 1.0000x reference)
//
#include <hip/hip_runtime.h>
#include <hip/hip_bf16.h>
#include <float.h>

// GraphSAGE fused single kernel: masked-max agg + ReLU + concat + Linear.
// B=4, N=512, C=128, OUT=128.
//
// R5: ONE kernel, no workspace. Block = 512 thr (8 waves) owns 8 nodes:
//   phase 1: wave w ballot-compacts node's adjacency row, max-scans ~51
//            neighbors (float2 gathers, 4-unrolled), writes bf16 combined
//            row [self|relu(max)] into LDS.
//   phase 2: wave w computes MFMA 16x16 n-tile w over a half-filled A
//            (rows 8..15 zeroed), B-frag built from fp32 W (L2-hot).
// Removes: comb ws round-trip, 2nd launch + graph gap.

#define Bsz 4
#define Nn  512
#define Cc  128
#define OUTn 128
#define NNODES (Bsz * Nn)   // 2048
#define KK (2 * Cc)         // 256
#define ROWP 264            // LDS row stride (bf16 elems): +8 pad -> bank spread

typedef __bf16 bf16x8 __attribute__((ext_vector_type(8)));
typedef float  f32x4  __attribute__((ext_vector_type(4)));

static __device__ __forceinline__ unsigned short f2bf(float x) {
    __hip_bfloat16 h = __float2bfloat16(x);
    return *reinterpret_cast<unsigned short*>(&h);
}
static __device__ __forceinline__ __bf16 f2bf16(float x) {
    unsigned short u = f2bf(x);
    return *reinterpret_cast<__bf16*>(&u);
}

__global__ __launch_bounds__(512) void sage_fused(
    const float* __restrict__ adj,
    const float* __restrict__ feat,
    const float* __restrict__ W,      // fp32 [256][128]
    const float* __restrict__ bias,
    float* __restrict__ out)          // fp32 [2048][128]
{
    const int w = threadIdx.x >> 6;   // 0..7 : wave = node slot = n-tile
    const int l = threadIdx.x & 63;
    const int node = blockIdx.x * 8 + w;
    const int b = node >> 9;
    const int i = node & (Nn - 1);

    __shared__ unsigned short nbr[8][Nn];        // compacted neighbor indices
    __shared__ unsigned short s_comb[16][ROWP];  // bf16 A-tile, rows 8..15 zero

    // Zero A-tile rows 8..15 (1056 dwords) while phase 1 runs.
    {
        unsigned int* z = (unsigned int*)&s_comb[8][0];
        for (int idx = threadIdx.x; idx < 8 * ROWP / 2; idx += 512) z[idx] = 0u;
    }

    // ---- phase 1: aggregation (one wave per node, full row) ----
    const float* adjrow = adj + (size_t)node * Nn;
    const float2* f2 = (const float2*)(feat + (size_t)b * Nn * Cc);

    int cnt = 0;
    #pragma unroll
    for (int ch = 0; ch < Nn / 64; ++ch) {
        int j = ch * 64 + l;
        float a = adjrow[j];
        unsigned long long mask = __ballot(a > 0.0f);
        int pos = __popcll(mask & ((1ull << l) - 1ull));
        if (a > 0.0f) nbr[w][cnt + pos] = (unsigned short)j;
        cnt += __popcll(mask);
    }
    // Same-wave DS write->read: HW lgkmcnt ordering guarantees visibility.

    float m0 = -FLT_MAX, m1 = -FLT_MAX;
    int k = 0;
    for (; k + 4 <= cnt; k += 4) {
        int j0 = nbr[w][k + 0], j1 = nbr[w][k + 1];
        int j2 = nbr[w][k + 2], j3 = nbr[w][k + 3];
        float2 v0 = f2[j0 * 64 + l];
        float2 v1 = f2[j1 * 64 + l];
        float2 v2 = f2[j2 * 64 + l];
        float2 v3 = f2[j3 * 64 + l];
        m0 = fmaxf(m0, fmaxf(fmaxf(v0.x, v1.x), fmaxf(v2.x, v3.x)));
        m1 = fmaxf(m1, fmaxf(fmaxf(v0.y, v1.y), fmaxf(v2.y, v3.y)));
    }
    for (; k < cnt; ++k) {
        int j = nbr[w][k];
        float2 v = f2[j * 64 + l];
        m0 = fmaxf(m0, v.x);
        m1 = fmaxf(m1, v.y);
    }

    // relu(max) covers the no-neighbor case (-FLT_MAX -> 0); matches the
    // reference since finfo.min is finite (its isfinite-guard never fires).
    float n0 = fmaxf(m0, 0.0f), n1 = fmaxf(m1, 0.0f);
    float2 s = f2[i * 64 + l];

    {
        ushort2* crow = (ushort2*)&s_comb[w][0];
        ushort2 sv; sv.x = f2bf(s.x); sv.y = f2bf(s.y);
        ushort2 nv; nv.x = f2bf(n0);  nv.y = f2bf(n1);
        crow[l]      = sv;   // self  channels [2l, 2l+1]
        crow[64 + l] = nv;   // neigh channels [128+2l, 128+2l+1]
    }
    __syncthreads();

    // ---- phase 2: GEMM tile. out[8 rows][nt*16 .. +16) for nt = w ----
    // A-frag: lane holds A[m=lane&15][k=koff+j] -> ds_read_b128 from s_comb.
    // B-frag: lane holds B[k=koff+j][n=nt*16+(lane&15)] from fp32 W + cvt.
    // C/D: col = lane&15, row = (lane>>4)*4 + reg  [measured m89/m91]
    const int nt = w;
    const int frow = l & 15;
    const int koff = (l >> 4) * 8;
    const float* wp = W + nt * 16 + frow;   // stride OUTn over k

    f32x4 acc = {0.f, 0.f, 0.f, 0.f};
    #pragma unroll
    for (int ks = 0; ks < KK / 32; ++ks) {
        bf16x8 af = *(const bf16x8*)&s_comb[frow][ks * 32 + koff];
        bf16x8 bfr;
        #pragma unroll
        for (int j = 0; j < 8; ++j) {
            bfr[j] = f2bf16(wp[(size_t)(ks * 32 + koff + j) * OUTn]);
        }
        acc = __builtin_amdgcn_mfma_f32_16x16x32_bf16(af, bfr, acc, 0, 0, 0);
    }

    const int col = l & 15;
    const int r0  = (l >> 4) * 4;           // rows r0..r0+3; valid if < 8
    const float bv = bias[nt * 16 + col];
    #pragma unroll
    for (int r = 0; r < 4; ++r) {
        int row = r0 + r;
        if (row < 8) {
            out[(size_t)(blockIdx.x * 8 + row) * OUTn + nt * 16 + col] = acc[r] + bv;
        }
    }
}

extern "C" void kernel_launch(void* const* d_in, const int* in_sizes, int n_in,
                              void* d_out, int out_size, void* d_ws, size_t ws_size,
                              hipStream_t stream) {
    const float* adj  = (const float*)d_in[0];
    const float* feat = (const float*)d_in[1];
    const float* W    = (const float*)d_in[2];
    const float* bias = (const float*)d_in[3];
    float* out = (float*)d_out;

    sage_fused<<<dim3(NNODES / 8), dim3(512), 0, stream>>>(adj, feat, W, bias, out);
}